// Round 13
// baseline (169.000 us; speedup 1.0000x reference)
//
#include <hip/hip_runtime.h>
#include <hip/hip_bf16.h>

typedef __attribute__((ext_vector_type(4))) float f32x4;
typedef __attribute__((ext_vector_type(8))) short bf16x8;

#define NV 100000
#define NC 1024
#define NTILE 1563          // ceil(NV/64)
#define SGRID 512           // persistent grid for the three heavy kernels
#define STATS_BLOCKS 128

__device__ __forceinline__ unsigned short f2bf(float f) {
  __hip_bfloat16 h = __float2bfloat16(f);
  return __builtin_bit_cast(unsigned short, h);
}
__device__ __forceinline__ float bf2f(unsigned short u) {
  return __builtin_bit_cast(float, ((unsigned)u) << 16);
}

// ---------------- K0: W1^T, W2^T, feat -> bf16; cent -> float4 ----------------
__global__ void k_prep(const float* __restrict__ W1, const float* __restrict__ W2,
                       const float* __restrict__ cent, const float* __restrict__ feat,
                       unsigned short* __restrict__ wt1, unsigned short* __restrict__ wt2,
                       float4* __restrict__ cent4, unsigned short* __restrict__ featb) {
  int gid = blockIdx.x * 256 + threadIdx.x;     // grid 64 -> 16384 threads
  if (gid < 128 * 128) {
    int j = gid >> 7, k = gid & 127;
    wt1[gid] = f2bf(W1[k * 128 + j]);   // W1 is [131][128]; rows >=128 multiply zeros
    wt2[gid] = f2bf(W2[k * 128 + j]);
  }
  if (gid < NC)
    cent4[gid] = make_float4(cent[gid * 3], cent[gid * 3 + 1], cent[gid * 3 + 2], 0.f);
  {  // feat -> bf16, 8 elems per thread (16384*8 = 131072 = 1024*128)
    int base = gid * 8;
    f32x4 a = *reinterpret_cast<const f32x4*>(feat + base);
    f32x4 b = *reinterpret_cast<const f32x4*>(feat + base + 4);
    bf16x8 o;
#pragma unroll
    for (int e = 0; e < 4; ++e) { o[e] = (short)f2bf(a[e]); o[4 + e] = (short)f2bf(b[e]); }
    *reinterpret_cast<bf16x8*>(featb + base) = o;
  }
}

// ---------------- K1: persistent 3-NN screening + f64 refine ----------------
__global__ __launch_bounds__(256, 4) void k_screen(
    const float* __restrict__ vert, const float4* __restrict__ cent4,
    int4* __restrict__ wi4, float4* __restrict__ wgt4) {
  __shared__ double rd2[64][13];
  __shared__ int    ridx[64][13];

  const int tid = threadIdx.x;
  const int lane = tid & 63;
  const int wv = tid >> 6;
  const int jb = __builtin_amdgcn_readfirstlane(wv * 256);
  const float4* cb = cent4 + jb;

  for (int t = blockIdx.x; t < NTILE; t += SGRID) {
    const int vtx = t * 64 + lane;
    const bool valid = vtx < NV;
    float vx = 0.f, vy = 0.f, vz = 0.f;
    if (valid) { vx = vert[vtx * 3]; vy = vert[vtx * 3 + 1]; vz = vert[vtx * 3 + 2]; }

    unsigned p0 = ~0u, p1 = ~0u, p2 = ~0u;
    unsigned q0 = ~0u, q1 = ~0u, q2 = ~0u;
    unsigned r0 = ~0u, r1 = ~0u, r2 = ~0u;
    unsigned u0 = ~0u, u1 = ~0u, u2 = ~0u;
#pragma unroll 2
    for (int j = 0; j < 256; j += 4) {
      float4 c0 = cb[j], c1 = cb[j + 1], c2 = cb[j + 2], c3 = cb[j + 3];
      unsigned m, M;
      {
        float dx = vx - c0.x, dy = vy - c0.y, dz = vz - c0.z;
        float dd = fmaf(dz, dz, fmaf(dy, dy, dx * dx));
        unsigned k = (__builtin_bit_cast(unsigned, dd) & 0xFFFFFF00u) | (unsigned)j;
        m = min(k, p0); M = max(k, p0); p0 = m;
        m = min(M, p1); M = max(M, p1); p1 = m;
        p2 = min(M, p2);
      }
      {
        float dx = vx - c1.x, dy = vy - c1.y, dz = vz - c1.z;
        float dd = fmaf(dz, dz, fmaf(dy, dy, dx * dx));
        unsigned k = (__builtin_bit_cast(unsigned, dd) & 0xFFFFFF00u) | (unsigned)(j + 1);
        m = min(k, q0); M = max(k, q0); q0 = m;
        m = min(M, q1); M = max(M, q1); q1 = m;
        q2 = min(M, q2);
      }
      {
        float dx = vx - c2.x, dy = vy - c2.y, dz = vz - c2.z;
        float dd = fmaf(dz, dz, fmaf(dy, dy, dx * dx));
        unsigned k = (__builtin_bit_cast(unsigned, dd) & 0xFFFFFF00u) | (unsigned)(j + 2);
        m = min(k, r0); M = max(k, r0); r0 = m;
        m = min(M, r1); M = max(M, r1); r1 = m;
        r2 = min(M, r2);
      }
      {
        float dx = vx - c3.x, dy = vy - c3.y, dz = vz - c3.z;
        float dd = fmaf(dz, dz, fmaf(dy, dy, dx * dx));
        unsigned k = (__builtin_bit_cast(unsigned, dd) & 0xFFFFFF00u) | (unsigned)(j + 3);
        m = min(k, u0); M = max(k, u0); u0 = m;
        m = min(M, u1); M = max(M, u1); u1 = m;
        u2 = min(M, u2);
      }
    }

    {
#pragma clang fp contract(off)
      const double dvx = (double)vx, dvy = (double)vy, dvz = (double)vz;
      const double sv64 = (dvx * dvx + dvy * dvy) + dvz * dvz;
      double e0 = INFINITY, e1 = INFINITY, e2 = INFINITY;
      int x0 = 0x7fffffff, x1 = 0x7fffffff, x2 = 0x7fffffff;
      const unsigned cand[12] = {p0, p1, p2, q0, q1, q2, r0, r1, r2, u0, u1, u2};
#pragma unroll
      for (int c = 0; c < 12; ++c) {
        int ix = jb + (int)(cand[c] & 0xFFu);
        float4 cf = cent4[ix];
        double cx = (double)cf.x, cy = (double)cf.y, cz = (double)cf.z;
        double sc2 = (cx * cx + cy * cy) + cz * cz;
        double dot = (dvx * cx + dvy * cy) + dvz * cz;
        double dd = (sv64 + sc2) - 2.0 * dot;
        if (dd < e2 || (dd == e2 && ix < x2)) {
          if (dd < e1 || (dd == e1 && ix < x1)) {
            e2 = e1; x2 = x1;
            if (dd < e0 || (dd == e0 && ix < x0)) { e1 = e0; x1 = x0; e0 = dd; x0 = ix; }
            else { e1 = dd; x1 = ix; }
          } else { e2 = dd; x2 = ix; }
        }
      }
      rd2[lane][wv * 3 + 0] = e0; rd2[lane][wv * 3 + 1] = e1; rd2[lane][wv * 3 + 2] = e2;
      ridx[lane][wv * 3 + 0] = x0; ridx[lane][wv * 3 + 1] = x1; ridx[lane][wv * 3 + 2] = x2;
    }
    __syncthreads();

    if (wv == 0 && valid) {
      double e0 = INFINITY, e1 = INFINITY, e2 = INFINITY;
      int x0 = 0x7fffffff, x1 = 0x7fffffff, x2 = 0x7fffffff;
#pragma unroll
      for (int c = 0; c < 12; ++c) {
        double dd = rd2[lane][c];
        int ix = ridx[lane][c];
        if (dd < e2 || (dd == e2 && ix < x2)) {
          if (dd < e1 || (dd == e1 && ix < x1)) {
            e2 = e1; x2 = x1;
            if (dd < e0 || (dd == e0 && ix < x0)) { e1 = e0; x1 = x0; e0 = dd; x0 = ix; }
            else { e1 = dd; x1 = ix; }
          } else { e2 = dd; x2 = ix; }
        }
      }
      double s0 = sqrt(fmax(e0, 0.0)), s1 = sqrt(fmax(e1, 0.0)), s2 = sqrt(fmax(e2, 0.0));
      float w0f, w1f, w2f;
      if (s0 == 0.0) { w0f = 1.f; w1f = 0.f; w2f = 0.f; }   // exact match: copy nearest
      else {
        double g0 = 1.0 / (s0 * s0), g1 = 1.0 / (s1 * s1), g2 = 1.0 / (s2 * s2);
        double rsd = 1.0 / (g0 + g1 + g2);
        w0f = (float)(g0 * rsd); w1f = (float)(g1 * rsd); w2f = (float)(g2 * rsd);
      }
      wi4[vtx]  = make_int4(x0, x1, x2, 0);
      wgt4[vtx] = make_float4(w0f, w1f, w2f, 0.f);
    }
    __syncthreads();   // protect rd2/ridx reuse by next tile iteration
  }
}

// ---------------- K2: persistent gather-interp GEMM1 (weights in registers) ----------------
template <bool BF16H>
__global__ __launch_bounds__(256, 2) void k_gemm1(
    const unsigned short* __restrict__ featb, const unsigned short* __restrict__ wt1,
    const float* __restrict__ b1, const int4* __restrict__ wi4,
    const float4* __restrict__ wgt4, float* __restrict__ H1,
    unsigned short* __restrict__ H1B) {
  const int tid = threadIdx.x;
  const int lane = tid & 63;
  const int wv = tid >> 6;
  const int jj = lane & 15, kg = lane >> 4;

  // hoist W1^T fragments (tile-invariant): 32 x bf16x8 = 128 VGPR
  bf16x8 aw[4][8];
#pragma unroll
  for (int ks = 0; ks < 4; ++ks)
#pragma unroll
    for (int n = 0; n < 8; ++n)
      aw[ks][n] = *reinterpret_cast<const bf16x8*>(
          wt1 + (n * 16 + jj) * 128 + ks * 32 + kg * 8);

  for (int t = blockIdx.x; t < NTILE; t += SGRID) {
    const int v = t * 64 + wv * 16 + jj;
    const bool valid = v < NV;
    const int vc = valid ? v : NV - 1;
    int4 wi = wi4[vc];
    float4 wg = wgt4[vc];

    bf16x8 bh[4];
#pragma unroll
    for (int ks = 0; ks < 4; ++ks) {
      const int off = ks * 32 + kg * 8;
      bf16x8 a = *reinterpret_cast<const bf16x8*>(featb + (size_t)wi.x * 128 + off);
      bf16x8 c = *reinterpret_cast<const bf16x8*>(featb + (size_t)wi.y * 128 + off);
      bf16x8 g = *reinterpret_cast<const bf16x8*>(featb + (size_t)wi.z * 128 + off);
      bf16x8 o;
#pragma unroll
      for (int e = 0; e < 8; ++e)
        o[e] = (short)f2bf(wg.x * bf2f((unsigned short)a[e]) +
                           wg.y * bf2f((unsigned short)c[e]) +
                           wg.z * bf2f((unsigned short)g[e]));
      bh[ks] = o;
    }

    f32x4 acc[8];
#pragma unroll
    for (int n = 0; n < 8; ++n) acc[n] = (f32x4){0.f, 0.f, 0.f, 0.f};
#pragma unroll
    for (int ks = 0; ks < 4; ++ks)
#pragma unroll
      for (int n = 0; n < 8; ++n)
        acc[n] = __builtin_amdgcn_mfma_f32_16x16x32_bf16(aw[ks][n], bh[ks], acc[n], 0, 0, 0);

    if (valid) {
#pragma unroll
      for (int n = 0; n < 8; ++n) {
        f32x4 b1v = *reinterpret_cast<const f32x4*>(b1 + n * 16 + kg * 4);
        f32x4 h = acc[n] + b1v;     // h[r] = h1[v][n*16+kg*4+r]
        if (BF16H) {
          ushort4 pk = make_ushort4(f2bf(h[0]), f2bf(h[1]), f2bf(h[2]), f2bf(h[3]));
          *reinterpret_cast<ushort4*>(H1B + (size_t)v * 128 + n * 16 + kg * 4) = pk;
        } else {
          *reinterpret_cast<f32x4*>(H1 + (size_t)v * 128 + n * 16 + kg * 4) = h;
        }
      }
    }
  }
}

// ---------------- K3: column sums / sumsq of h1 (deterministic 2-stage) ----------------
template <bool BF16H>
__global__ __launch_bounds__(256) void k_stats(
    const unsigned short* __restrict__ H1B, const float* __restrict__ H1,
    float* __restrict__ partials2) {
  __shared__ float ls[16][129];
  __shared__ float ls2[16][129];
  const int t = threadIdx.x;
  const int rl = t >> 4, g = t & 15;
  float s[8], s2[8];
#pragma unroll
  for (int e = 0; e < 8; ++e) { s[e] = 0.f; s2[e] = 0.f; }
  for (int r = blockIdx.x * 16 + rl; r < NV; r += STATS_BLOCKS * 16) {
    if (BF16H) {
      bf16x8 v = *reinterpret_cast<const bf16x8*>(H1B + (size_t)r * 128 + g * 8);
#pragma unroll
      for (int e = 0; e < 8; ++e) {
        float f = bf2f((unsigned short)v[e]);
        s[e] += f; s2[e] += f * f;
      }
    } else {
      f32x4 a = *reinterpret_cast<const f32x4*>(H1 + (size_t)r * 128 + g * 8);
      f32x4 b = *reinterpret_cast<const f32x4*>(H1 + (size_t)r * 128 + g * 8 + 4);
#pragma unroll
      for (int e = 0; e < 4; ++e) {
        s[e] += a[e]; s2[e] += a[e] * a[e];
        s[4 + e] += b[e]; s2[4 + e] += b[e] * b[e];
      }
    }
  }
#pragma unroll
  for (int e = 0; e < 8; ++e) { ls[rl][g * 8 + e] = s[e]; ls2[rl][g * 8 + e] = s2[e]; }
  __syncthreads();
  if (t < 128) {
    float a = 0.f, b = 0.f;
#pragma unroll
    for (int k = 0; k < 16; ++k) { a += ls[k][t]; b += ls2[k][t]; }
    partials2[(size_t)blockIdx.x * 256 + t] = a;
    partials2[(size_t)blockIdx.x * 256 + 128 + t] = b;
  }
}

__global__ void k_red2(const float* __restrict__ partials2, const float* __restrict__ gamma,
                       const float* __restrict__ beta, float* __restrict__ ash) {
  const int t = threadIdx.x;  // 256
  double s = 0.0;
  for (int b = 0; b < STATS_BLOCKS; ++b) s += (double)partials2[b * 256 + t];
  __shared__ double sums[256];
  sums[t] = s;
  __syncthreads();
  if (t < 128) {
    double mu  = sums[t] * (1.0 / (double)NV);
    double var = sums[t + 128] * (1.0 / (double)NV) - mu * mu;  // biased, like torch BN
    float af = gamma[t] / sqrtf((float)var + 1e-5f);
    ash[t]       = af;
    ash[128 + t] = beta[t] - (float)mu * af;
  }
}

// ---------------- K4: persistent GEMM2 + full-line LDS re-tile epilogue ----------------
template <bool BF16H>
__global__ __launch_bounds__(256, 2) void k_gemm2(
    const unsigned short* __restrict__ wt2, const float* __restrict__ b2,
    const float* __restrict__ ash, float* __restrict__ HX,
    const unsigned short* __restrict__ H1B, const float* __restrict__ H1) {
  __shared__ float ldso[4][2048];   // 32 KB: per-wave 16x128 f32 out tile
  const int tid = threadIdx.x;
  const int lane = tid & 63, wv = tid >> 6;
  const int jj = lane & 15, kg = lane >> 4;

  // hoist W2^T fragments (tile-invariant)
  bf16x8 aw[4][8];
#pragma unroll
  for (int ks = 0; ks < 4; ++ks)
#pragma unroll
    for (int n = 0; n < 8; ++n)
      aw[ks][n] = *reinterpret_cast<const bf16x8*>(
          wt2 + (n * 16 + jj) * 128 + ks * 32 + kg * 8);

  for (int t = blockIdx.x; t < NTILE; t += SGRID) {
    const int v = t * 64 + wv * 16 + jj;
    const size_t rb = (size_t)(v < NV ? v : NV - 1) * 128;

    bf16x8 bh[4];
#pragma unroll
    for (int ks = 0; ks < 4; ++ks) {
      const int k0 = ks * 32 + kg * 8;
      f32x4 sa0 = *reinterpret_cast<const f32x4*>(ash + k0);
      f32x4 sa1 = *reinterpret_cast<const f32x4*>(ash + k0 + 4);
      f32x4 sb0 = *reinterpret_cast<const f32x4*>(ash + 128 + k0);
      f32x4 sb1 = *reinterpret_cast<const f32x4*>(ash + 128 + k0 + 4);
      bf16x8 af;
      if (BF16H) {
        bf16x8 hv = *reinterpret_cast<const bf16x8*>(H1B + rb + k0);
#pragma unroll
        for (int e = 0; e < 4; ++e) {
          float h0 = bf2f((unsigned short)hv[e]);
          float h1 = bf2f((unsigned short)hv[4 + e]);
          af[e]     = (short)f2bf(fmaxf(h0 * sa0[e] + sb0[e], 0.f));
          af[4 + e] = (short)f2bf(fmaxf(h1 * sa1[e] + sb1[e], 0.f));
        }
      } else {
        f32x4 h0 = *reinterpret_cast<const f32x4*>(H1 + rb + k0);
        f32x4 h1 = *reinterpret_cast<const f32x4*>(H1 + rb + k0 + 4);
#pragma unroll
        for (int e = 0; e < 4; ++e) {
          af[e]     = (short)f2bf(fmaxf(h0[e] * sa0[e] + sb0[e], 0.f));
          af[4 + e] = (short)f2bf(fmaxf(h1[e] * sa1[e] + sb1[e], 0.f));
        }
      }
      bh[ks] = af;
    }

    f32x4 acc[8];
#pragma unroll
    for (int n = 0; n < 8; ++n) acc[n] = (f32x4){0.f, 0.f, 0.f, 0.f};
#pragma unroll
    for (int ks = 0; ks < 4; ++ks)
#pragma unroll
      for (int n = 0; n < 8; ++n)
        acc[n] = __builtin_amdgcn_mfma_f32_16x16x32_bf16(aw[ks][n], bh[ks], acc[n], 0, 0, 0);

    // stage to LDS (XOR-swizzled 16B slots; per-wave private, wave-coherent)
#pragma unroll
    for (int n = 0; n < 8; ++n) {
      f32x4 b2v = *reinterpret_cast<const f32x4*>(b2 + n * 16 + kg * 4);
      f32x4 o = acc[n] + b2v;     // cols n*16+kg*4 .. +3 of row jj
      const int slot = n * 4 + kg;
      *reinterpret_cast<f32x4*>(&ldso[wv][jj * 128 + ((slot ^ (jj & 7)) << 2)]) = o;
    }
    // coalesced full-line stores: 8 x (64 lanes x 16B = 1KB contiguous)
    const int vbase = t * 64 + wv * 16;
#pragma unroll
    for (int i = 0; i < 8; ++i) {
      const int fo = i * 256 + lane * 4;        // 0..2044, float offset in tile
      const int row = fo >> 7;
      const int slot = (fo >> 2) & 31;
      f32x4 val = *reinterpret_cast<const f32x4*>(
          &ldso[wv][row * 128 + ((slot ^ (row & 7)) << 2)]);
      if (vbase + row < NV)
        *reinterpret_cast<f32x4*>(HX + (size_t)(vbase + row) * 128 + (fo & 127)) = val;
    }
  }
}

extern "C" void kernel_launch(void* const* d_in, const int* in_sizes, int n_in,
                              void* d_out, int out_size, void* d_ws, size_t ws_size,
                              hipStream_t stream) {
  const float* vert  = (const float*)d_in[0];
  const float* cent  = (const float*)d_in[1];
  const float* feat  = (const float*)d_in[2];
  const float* W1    = (const float*)d_in[3];
  const float* b1    = (const float*)d_in[4];
  const float* gamma = (const float*)d_in[5];
  const float* beta  = (const float*)d_in[6];
  const float* W2    = (const float*)d_in[7];
  const float* b2    = (const float*)d_in[8];
  float* out = (float*)d_out;
  char* ws = (char*)d_ws;

  float* partials2 = (float*)ws;                                   // 128 KB
  unsigned short* wt1 = (unsigned short*)(ws + 256 * 1024);        // 32 KB
  unsigned short* wt2 = wt1 + 128 * 128;                           // 32 KB
  float* ash = (float*)(ws + 384 * 1024);                          // 1 KB
  float4* cent4 = (float4*)(ws + 512 * 1024);                      // 16 KB
  unsigned short* featb = (unsigned short*)(ws + 576 * 1024);      // 256 KB
  int4* wi4 = (int4*)(ws + (1u << 20));                            // 1.6 MB
  float4* wgt4 = (float4*)(ws + (3u << 20));                       // 1.6 MB
  unsigned short* h1b = (unsigned short*)(ws + (5u << 20));        // 25.6 MB
  const bool bf16h = ws_size >= (size_t)(5u << 20) + (size_t)NV * 128 * 2 + (1u << 16);

  k_prep<<<64, 256, 0, stream>>>(W1, W2, cent, feat, wt1, wt2, cent4, featb);
  k_screen<<<SGRID, 256, 0, stream>>>(vert, cent4, wi4, wgt4);
  if (bf16h) {
    k_gemm1<true><<<SGRID, 256, 0, stream>>>(featb, wt1, b1, wi4, wgt4, out, h1b);
    k_stats<true><<<STATS_BLOCKS, 256, 0, stream>>>(h1b, out, partials2);
    k_red2<<<1, 256, 0, stream>>>(partials2, gamma, beta, ash);
    k_gemm2<true><<<SGRID, 256, 0, stream>>>(wt2, b2, ash, out, h1b, out);
  } else {
    k_gemm1<false><<<SGRID, 256, 0, stream>>>(featb, wt1, b1, wi4, wgt4, out, h1b);
    k_stats<false><<<STATS_BLOCKS, 256, 0, stream>>>(h1b, out, partials2);
    k_red2<<<1, 256, 0, stream>>>(partials2, gamma, beta, ash);
    k_gemm2<false><<<SGRID, 256, 0, stream>>>(wt2, b2, ash, out, h1b, out);
  }
}

// Round 14
// 150.785 us; speedup vs baseline: 1.1208x; 1.1208x over previous
//
#include <hip/hip_runtime.h>
#include <hip/hip_bf16.h>

typedef __attribute__((ext_vector_type(4))) float f32x4;
typedef __attribute__((ext_vector_type(8))) short bf16x8;

#define NV 100000
#define NC 1024
#define NTILE 1563          // ceil(NV/64)
#define SGRID2 512          // persistent grid for gemm2
#define STATS_BLOCKS 128

__device__ __forceinline__ unsigned short f2bf(float f) {
  __hip_bfloat16 h = __float2bfloat16(f);
  return __builtin_bit_cast(unsigned short, h);
}
__device__ __forceinline__ float bf2f(unsigned short u) {
  return __builtin_bit_cast(float, ((unsigned)u) << 16);
}

// ---------------- K0: W1^T, W2^T, feat -> bf16; cent -> float4 ----------------
__global__ void k_prep(const float* __restrict__ W1, const float* __restrict__ W2,
                       const float* __restrict__ cent, const float* __restrict__ feat,
                       unsigned short* __restrict__ wt1, unsigned short* __restrict__ wt2,
                       float4* __restrict__ cent4, unsigned short* __restrict__ featb) {
  int gid = blockIdx.x * 256 + threadIdx.x;     // grid 64 -> 16384 threads
  if (gid < 128 * 128) {
    int j = gid >> 7, k = gid & 127;
    wt1[gid] = f2bf(W1[k * 128 + j]);   // W1 is [131][128]; rows >=128 multiply zeros
    wt2[gid] = f2bf(W2[k * 128 + j]);
  }
  if (gid < NC)
    cent4[gid] = make_float4(cent[gid * 3], cent[gid * 3 + 1], cent[gid * 3 + 2], 0.f);
  {  // feat -> bf16, 8 elems per thread (16384*8 = 131072 = 1024*128)
    int base = gid * 8;
    f32x4 a = *reinterpret_cast<const f32x4*>(feat + base);
    f32x4 b = *reinterpret_cast<const f32x4*>(feat + base + 4);
    bf16x8 o;
#pragma unroll
    for (int e = 0; e < 4; ++e) { o[e] = (short)f2bf(a[e]); o[4 + e] = (short)f2bf(b[e]); }
    *reinterpret_cast<bf16x8*>(featb + base) = o;
  }
}

// ---------------- K1: fused screen + f64 refine + gather-interp + GEMM1 ----------------
// ph2: branchless f32 screening (4 streams x top-3, packed keys, per-wave
//      256-centroid partition via scalar-uniform cent4 base).
// ph3a: per-thread f64 refine of its 12 candidates (np-identical expansion,
//      contract off) -> partial top-3 per (vertex, partition) into LDS.
// [one barrier]
// ph3b: each thread merges the 12 partial candidates OF ITS GEMM VERTEX
//      (m = wv*16+jj) in f64 with index tie-break -> weights in registers.
// ph4: 12 bf16-feat gathers -> interp -> MFMA B-frags in registers.
// ph5: swapped-operand MFMA (A = W1^T) -> +b1 -> packed bf16 h1 stores.
template <bool BF16H>
__global__ __launch_bounds__(256, 4) void k_fused(
    const float* __restrict__ vert, const float4* __restrict__ cent4,
    const unsigned short* __restrict__ featb, const unsigned short* __restrict__ wt1,
    const float* __restrict__ b1, float* __restrict__ H1,
    unsigned short* __restrict__ H1B) {
  __shared__ double rd2[64][13];   // [vertex][partition*3+s], +pad
  __shared__ int    ridx[64][13];

  const int tid = threadIdx.x;
  const int lane = tid & 63;
  const int wv = tid >> 6;
  const int vtx0 = blockIdx.x * 64;
  const int vtx = vtx0 + lane;
  const bool valid = vtx < NV;

  float vx = 0.f, vy = 0.f, vz = 0.f;
  if (valid) { vx = vert[vtx * 3]; vy = vert[vtx * 3 + 1]; vz = vert[vtx * 3 + 2]; }

  const int jb = __builtin_amdgcn_readfirstlane(wv * 256);
  const float4* cb = cent4 + jb;

  // ---- ph2: branchless screening, 4 streams x top-3 of 64 each
  unsigned p0 = ~0u, p1 = ~0u, p2 = ~0u;
  unsigned q0 = ~0u, q1 = ~0u, q2 = ~0u;
  unsigned r0 = ~0u, r1 = ~0u, r2 = ~0u;
  unsigned u0 = ~0u, u1 = ~0u, u2 = ~0u;
#pragma unroll 2
  for (int j = 0; j < 256; j += 4) {
    float4 c0 = cb[j], c1 = cb[j + 1], c2 = cb[j + 2], c3 = cb[j + 3];
    unsigned m, M;
    {
      float dx = vx - c0.x, dy = vy - c0.y, dz = vz - c0.z;
      float dd = fmaf(dz, dz, fmaf(dy, dy, dx * dx));
      unsigned k = (__builtin_bit_cast(unsigned, dd) & 0xFFFFFF00u) | (unsigned)j;
      m = min(k, p0); M = max(k, p0); p0 = m;
      m = min(M, p1); M = max(M, p1); p1 = m;
      p2 = min(M, p2);
    }
    {
      float dx = vx - c1.x, dy = vy - c1.y, dz = vz - c1.z;
      float dd = fmaf(dz, dz, fmaf(dy, dy, dx * dx));
      unsigned k = (__builtin_bit_cast(unsigned, dd) & 0xFFFFFF00u) | (unsigned)(j + 1);
      m = min(k, q0); M = max(k, q0); q0 = m;
      m = min(M, q1); M = max(M, q1); q1 = m;
      q2 = min(M, q2);
    }
    {
      float dx = vx - c2.x, dy = vy - c2.y, dz = vz - c2.z;
      float dd = fmaf(dz, dz, fmaf(dy, dy, dx * dx));
      unsigned k = (__builtin_bit_cast(unsigned, dd) & 0xFFFFFF00u) | (unsigned)(j + 2);
      m = min(k, r0); M = max(k, r0); r0 = m;
      m = min(M, r1); M = max(M, r1); r1 = m;
      r2 = min(M, r2);
    }
    {
      float dx = vx - c3.x, dy = vy - c3.y, dz = vz - c3.z;
      float dd = fmaf(dz, dz, fmaf(dy, dy, dx * dx));
      unsigned k = (__builtin_bit_cast(unsigned, dd) & 0xFFFFFF00u) | (unsigned)(j + 3);
      m = min(k, u0); M = max(k, u0); u0 = m;
      m = min(M, u1); M = max(M, u1); u1 = m;
      u2 = min(M, u2);
    }
  }

  // ---- ph3a: per-thread f64 refine of its own 12 candidates
  {
#pragma clang fp contract(off)
    const double dvx = (double)vx, dvy = (double)vy, dvz = (double)vz;
    const double sv64 = (dvx * dvx + dvy * dvy) + dvz * dvz;
    double e0 = INFINITY, e1 = INFINITY, e2 = INFINITY;
    int x0 = 0x7fffffff, x1 = 0x7fffffff, x2 = 0x7fffffff;
    const unsigned cand[12] = {p0, p1, p2, q0, q1, q2, r0, r1, r2, u0, u1, u2};
#pragma unroll
    for (int c = 0; c < 12; ++c) {
      int ix = jb + (int)(cand[c] & 0xFFu);
      float4 cf = cent4[ix];
      double cx = (double)cf.x, cy = (double)cf.y, cz = (double)cf.z;
      double sc2 = (cx * cx + cy * cy) + cz * cz;
      double dot = (dvx * cx + dvy * cy) + dvz * cz;
      double dd = (sv64 + sc2) - 2.0 * dot;
      if (dd < e2 || (dd == e2 && ix < x2)) {
        if (dd < e1 || (dd == e1 && ix < x1)) {
          e2 = e1; x2 = x1;
          if (dd < e0 || (dd == e0 && ix < x0)) { e1 = e0; x1 = x0; e0 = dd; x0 = ix; }
          else { e1 = dd; x1 = ix; }
        } else { e2 = dd; x2 = ix; }
      }
    }
    rd2[lane][wv * 3 + 0] = e0; rd2[lane][wv * 3 + 1] = e1; rd2[lane][wv * 3 + 2] = e2;
    ridx[lane][wv * 3 + 0] = x0; ridx[lane][wv * 3 + 1] = x1; ridx[lane][wv * 3 + 2] = x2;
  }
  __syncthreads();   // the only barrier

  // ---- ph3b: merge the 12 partials of this thread's GEMM vertex m
  const int jj = lane & 15, kg = lane >> 4;
  const int m = wv * 16 + jj;          // GEMM vertex within block
  const int v = vtx0 + m;
  const bool valid2 = v < NV;
  float w0f, w1f, w2f;
  int nn0, nn1, nn2;
  {
    double e0 = INFINITY, e1 = INFINITY, e2 = INFINITY;
    int x0 = 0x7fffffff, x1 = 0x7fffffff, x2 = 0x7fffffff;
#pragma unroll
    for (int c = 0; c < 12; ++c) {
      double dd = rd2[m][c];
      int ix = ridx[m][c];
      if (dd < e2 || (dd == e2 && ix < x2)) {
        if (dd < e1 || (dd == e1 && ix < x1)) {
          e2 = e1; x2 = x1;
          if (dd < e0 || (dd == e0 && ix < x0)) { e1 = e0; x1 = x0; e0 = dd; x0 = ix; }
          else { e1 = dd; x1 = ix; }
        } else { e2 = dd; x2 = ix; }
      }
    }
    double s0 = sqrt(fmax(e0, 0.0)), s1 = sqrt(fmax(e1, 0.0)), s2 = sqrt(fmax(e2, 0.0));
    if (s0 == 0.0) { w0f = 1.f; w1f = 0.f; w2f = 0.f; }   // exact match: copy nearest
    else {
      double g0 = 1.0 / (s0 * s0), g1 = 1.0 / (s1 * s1), g2 = 1.0 / (s2 * s2);
      double rsd = 1.0 / (g0 + g1 + g2);
      w0f = (float)(g0 * rsd); w1f = (float)(g1 * rsd); w2f = (float)(g2 * rsd);
    }
    nn0 = (x0 < NC) ? x0 : 0;   // invalid-vertex guard (bogus but in-bounds)
    nn1 = (x1 < NC) ? x1 : 0;
    nn2 = (x2 < NC) ? x2 : 0;
  }

  // ---- ph4: gathers -> interp -> B-frags in registers
  bf16x8 bh[4];
#pragma unroll
  for (int ks = 0; ks < 4; ++ks) {
    const int off = ks * 32 + kg * 8;
    bf16x8 a = *reinterpret_cast<const bf16x8*>(featb + (size_t)nn0 * 128 + off);
    bf16x8 c = *reinterpret_cast<const bf16x8*>(featb + (size_t)nn1 * 128 + off);
    bf16x8 g = *reinterpret_cast<const bf16x8*>(featb + (size_t)nn2 * 128 + off);
    bf16x8 o;
#pragma unroll
    for (int e = 0; e < 8; ++e)
      o[e] = (short)f2bf(w0f * bf2f((unsigned short)a[e]) +
                         w1f * bf2f((unsigned short)c[e]) +
                         w2f * bf2f((unsigned short)g[e]));
    bh[ks] = o;
  }

  // ---- ph5: swapped-operand MFMA + b1 + packed stores (r12-verified mapping)
  f32x4 acc[8];
#pragma unroll
  for (int n = 0; n < 8; ++n) acc[n] = (f32x4){0.f, 0.f, 0.f, 0.f};
#pragma unroll
  for (int ks = 0; ks < 4; ++ks) {
#pragma unroll
    for (int n = 0; n < 8; ++n) {
      bf16x8 aw = *reinterpret_cast<const bf16x8*>(
          wt1 + (n * 16 + jj) * 128 + ks * 32 + kg * 8);
      acc[n] = __builtin_amdgcn_mfma_f32_16x16x32_bf16(aw, bh[ks], acc[n], 0, 0, 0);
    }
  }
  if (valid2) {
#pragma unroll
    for (int n = 0; n < 8; ++n) {
      f32x4 b1v = *reinterpret_cast<const f32x4*>(b1 + n * 16 + kg * 4);
      f32x4 h = acc[n] + b1v;     // h[r] = h1[v][n*16+kg*4+r]
      if (BF16H) {
        ushort4 pk = make_ushort4(f2bf(h[0]), f2bf(h[1]), f2bf(h[2]), f2bf(h[3]));
        *reinterpret_cast<ushort4*>(H1B + (size_t)v * 128 + n * 16 + kg * 4) = pk;
      } else {
        *reinterpret_cast<f32x4*>(H1 + (size_t)v * 128 + n * 16 + kg * 4) = h;
      }
    }
  }
}

// ---------------- K3: column sums / sumsq of h1 (deterministic 2-stage) ----------------
template <bool BF16H>
__global__ __launch_bounds__(256) void k_stats(
    const unsigned short* __restrict__ H1B, const float* __restrict__ H1,
    float* __restrict__ partials2) {
  __shared__ float ls[16][129];
  __shared__ float ls2[16][129];
  const int t = threadIdx.x;
  const int rl = t >> 4, g = t & 15;
  float s[8], s2[8];
#pragma unroll
  for (int e = 0; e < 8; ++e) { s[e] = 0.f; s2[e] = 0.f; }
  for (int r = blockIdx.x * 16 + rl; r < NV; r += STATS_BLOCKS * 16) {
    if (BF16H) {
      bf16x8 v = *reinterpret_cast<const bf16x8*>(H1B + (size_t)r * 128 + g * 8);
#pragma unroll
      for (int e = 0; e < 8; ++e) {
        float f = bf2f((unsigned short)v[e]);
        s[e] += f; s2[e] += f * f;
      }
    } else {
      f32x4 a = *reinterpret_cast<const f32x4*>(H1 + (size_t)r * 128 + g * 8);
      f32x4 b = *reinterpret_cast<const f32x4*>(H1 + (size_t)r * 128 + g * 8 + 4);
#pragma unroll
      for (int e = 0; e < 4; ++e) {
        s[e] += a[e]; s2[e] += a[e] * a[e];
        s[4 + e] += b[e]; s2[4 + e] += b[e] * b[e];
      }
    }
  }
#pragma unroll
  for (int e = 0; e < 8; ++e) { ls[rl][g * 8 + e] = s[e]; ls2[rl][g * 8 + e] = s2[e]; }
  __syncthreads();
  if (t < 128) {
    float a = 0.f, b = 0.f;
#pragma unroll
    for (int k = 0; k < 16; ++k) { a += ls[k][t]; b += ls2[k][t]; }
    partials2[(size_t)blockIdx.x * 256 + t] = a;
    partials2[(size_t)blockIdx.x * 256 + 128 + t] = b;
  }
}

__global__ void k_red2(const float* __restrict__ partials2, const float* __restrict__ gamma,
                       const float* __restrict__ beta, float* __restrict__ ash) {
  const int t = threadIdx.x;  // 256
  double s = 0.0;
  for (int b = 0; b < STATS_BLOCKS; ++b) s += (double)partials2[b * 256 + t];
  __shared__ double sums[256];
  sums[t] = s;
  __syncthreads();
  if (t < 128) {
    double mu  = sums[t] * (1.0 / (double)NV);
    double var = sums[t + 128] * (1.0 / (double)NV) - mu * mu;  // biased, like torch BN
    float af = gamma[t] / sqrtf((float)var + 1e-5f);
    ash[t]       = af;
    ash[128 + t] = beta[t] - (float)mu * af;
  }
}

// ---------------- K4: persistent GEMM2 + full-line LDS re-tile epilogue ----------------
template <bool BF16H>
__global__ __launch_bounds__(256, 2) void k_gemm2(
    const unsigned short* __restrict__ wt2, const float* __restrict__ b2,
    const float* __restrict__ ash, float* __restrict__ HX,
    const unsigned short* __restrict__ H1B, const float* __restrict__ H1) {
  __shared__ float ldso[4][2048];   // 32 KB: per-wave 16x128 f32 out tile
  const int tid = threadIdx.x;
  const int lane = tid & 63, wv = tid >> 6;
  const int jj = lane & 15, kg = lane >> 4;

  // hoist W2^T fragments (tile-invariant)
  bf16x8 aw[4][8];
#pragma unroll
  for (int ks = 0; ks < 4; ++ks)
#pragma unroll
    for (int n = 0; n < 8; ++n)
      aw[ks][n] = *reinterpret_cast<const bf16x8*>(
          wt2 + (n * 16 + jj) * 128 + ks * 32 + kg * 8);

  for (int t = blockIdx.x; t < NTILE; t += SGRID2) {
    const int v = t * 64 + wv * 16 + jj;
    const size_t rb = (size_t)(v < NV ? v : NV - 1) * 128;

    bf16x8 bh[4];
#pragma unroll
    for (int ks = 0; ks < 4; ++ks) {
      const int k0 = ks * 32 + kg * 8;
      f32x4 sa0 = *reinterpret_cast<const f32x4*>(ash + k0);
      f32x4 sa1 = *reinterpret_cast<const f32x4*>(ash + k0 + 4);
      f32x4 sb0 = *reinterpret_cast<const f32x4*>(ash + 128 + k0);
      f32x4 sb1 = *reinterpret_cast<const f32x4*>(ash + 128 + k0 + 4);
      bf16x8 af;
      if (BF16H) {
        bf16x8 hv = *reinterpret_cast<const bf16x8*>(H1B + rb + k0);
#pragma unroll
        for (int e = 0; e < 4; ++e) {
          float h0 = bf2f((unsigned short)hv[e]);
          float h1 = bf2f((unsigned short)hv[4 + e]);
          af[e]     = (short)f2bf(fmaxf(h0 * sa0[e] + sb0[e], 0.f));
          af[4 + e] = (short)f2bf(fmaxf(h1 * sa1[e] + sb1[e], 0.f));
        }
      } else {
        f32x4 h0 = *reinterpret_cast<const f32x4*>(H1 + rb + k0);
        f32x4 h1 = *reinterpret_cast<const f32x4*>(H1 + rb + k0 + 4);
#pragma unroll
        for (int e = 0; e < 4; ++e) {
          af[e]     = (short)f2bf(fmaxf(h0[e] * sa0[e] + sb0[e], 0.f));
          af[4 + e] = (short)f2bf(fmaxf(h1[e] * sa1[e] + sb1[e], 0.f));
        }
      }
      bh[ks] = af;
    }

    f32x4 acc[8];
#pragma unroll
    for (int n = 0; n < 8; ++n) acc[n] = (f32x4){0.f, 0.f, 0.f, 0.f};
#pragma unroll
    for (int ks = 0; ks < 4; ++ks)
#pragma unroll
      for (int n = 0; n < 8; ++n)
        acc[n] = __builtin_amdgcn_mfma_f32_16x16x32_bf16(aw[ks][n], bh[ks], acc[n], 0, 0, 0);

    // stage to LDS (XOR-swizzled 16B slots; per-wave private, wave-coherent)
#pragma unroll
    for (int n = 0; n < 8; ++n) {
      f32x4 b2v = *reinterpret_cast<const f32x4*>(b2 + n * 16 + kg * 4);
      f32x4 o = acc[n] + b2v;     // cols n*16+kg*4 .. +3 of row jj
      const int slot = n * 4 + kg;
      *reinterpret_cast<f32x4*>(&ldso[wv][jj * 128 + ((slot ^ (jj & 7)) << 2)]) = o;
    }
    // coalesced full-line stores: 8 x (64 lanes x 16B = 1KB contiguous)
    const int vbase = t * 64 + wv * 16;
#pragma unroll
    for (int i = 0; i < 8; ++i) {
      const int fo = i * 256 + lane * 4;        // 0..2044, float offset in tile
      const int row = fo >> 7;
      const int slot = (fo >> 2) & 31;
      f32x4 val = *reinterpret_cast<const f32x4*>(
          &ldso[wv][row * 128 + ((slot ^ (row & 7)) << 2)]);
      if (vbase + row < NV)
        *reinterpret_cast<f32x4*>(HX + (size_t)(vbase + row) * 128 + (fo & 127)) = val;
    }
  }
}

extern "C" void kernel_launch(void* const* d_in, const int* in_sizes, int n_in,
                              void* d_out, int out_size, void* d_ws, size_t ws_size,
                              hipStream_t stream) {
  const float* vert  = (const float*)d_in[0];
  const float* cent  = (const float*)d_in[1];
  const float* feat  = (const float*)d_in[2];
  const float* W1    = (const float*)d_in[3];
  const float* b1    = (const float*)d_in[4];
  const float* gamma = (const float*)d_in[5];
  const float* beta  = (const float*)d_in[6];
  const float* W2    = (const float*)d_in[7];
  const float* b2    = (const float*)d_in[8];
  float* out = (float*)d_out;
  char* ws = (char*)d_ws;

  float* partials2 = (float*)ws;                                   // 128 KB
  unsigned short* wt1 = (unsigned short*)(ws + 256 * 1024);        // 32 KB
  unsigned short* wt2 = wt1 + 128 * 128;                           // 32 KB
  float* ash = (float*)(ws + 384 * 1024);                          // 1 KB
  float4* cent4 = (float4*)(ws + 512 * 1024);                      // 16 KB
  unsigned short* featb = (unsigned short*)(ws + 576 * 1024);      // 256 KB
  unsigned short* h1b = (unsigned short*)(ws + (1u << 20));        // 25.6 MB
  const bool bf16h = ws_size >= (size_t)(1u << 20) + (size_t)NV * 128 * 2 + (1u << 16);

  k_prep<<<64, 256, 0, stream>>>(W1, W2, cent, feat, wt1, wt2, cent4, featb);
  if (bf16h) {
    k_fused<true><<<NTILE, 256, 0, stream>>>(vert, cent4, featb, wt1, b1, out, h1b);
    k_stats<true><<<STATS_BLOCKS, 256, 0, stream>>>(h1b, out, partials2);
    k_red2<<<1, 256, 0, stream>>>(partials2, gamma, beta, ash);
    k_gemm2<true><<<SGRID2, 256, 0, stream>>>(wt2, b2, ash, out, h1b, out);
  } else {
    k_fused<false><<<NTILE, 256, 0, stream>>>(vert, cent4, featb, wt1, b1, out, h1b);
    k_stats<false><<<STATS_BLOCKS, 256, 0, stream>>>(h1b, out, partials2);
    k_red2<<<1, 256, 0, stream>>>(partials2, gamma, beta, ash);
    k_gemm2<false><<<SGRID2, 256, 0, stream>>>(wt2, b2, ash, out, h1b, out);
  }
}